// Round 10
// baseline (95.261 us; speedup 1.0000x reference)
//
#include <hip/hip_runtime.h>
#include <hip/hip_bf16.h>
#include <cstddef>

#define B_  8
#define CQ  256
#define CC  512
#define N_  1024   // Hq*Wq
#define HQ  32
#define WQ  32
#define NH  8
#define HD  32

typedef __bf16 bf16x8 __attribute__((ext_vector_type(8)));
typedef float f32x4 __attribute__((ext_vector_type(4)));
typedef float f32x16 __attribute__((ext_vector_type(16)));
typedef unsigned int uint4v __attribute__((ext_vector_type(4)));
typedef unsigned short ushort8 __attribute__((ext_vector_type(8)));
typedef unsigned short ushort4v __attribute__((ext_vector_type(4)));

__device__ __forceinline__ unsigned short f2bf(float x) {
    return __builtin_bit_cast(unsigned short, __float2bfloat16(x));
}
__device__ __forceinline__ bf16x8 ldb8(const unsigned short* p) {
    return __builtin_bit_cast(bf16x8, *(const ushort8*)p);
}

// ---------------------------------------------------------------------------
// Weight transposes f32->bf16: W (K x 256) -> Wt (256 x K). grid (16,8,4).
// ---------------------------------------------------------------------------
__global__ __launch_bounds__(256) void wt_conv_all_k(
    const float* __restrict__ Wq, const float* __restrict__ Wk,
    const float* __restrict__ Wv, const float* __restrict__ Wo,
    __hip_bfloat16* __restrict__ Wqt, __hip_bfloat16* __restrict__ Wkt,
    __hip_bfloat16* __restrict__ Wvt, __hip_bfloat16* __restrict__ Wot) {
    __shared__ float T[32][33];
    const float* W; __hip_bfloat16* Wt; int K;
    switch (blockIdx.z) {
        case 0: W = Wq; Wt = Wqt; K = CQ; break;
        case 1: W = Wk; Wt = Wkt; K = CC; break;
        case 2: W = Wv; Wt = Wvt; K = CC; break;
        default: W = Wo; Wt = Wot; K = CQ; break;
    }
    const int k0 = blockIdx.x * 32;
    if (k0 >= K) return;
    const int c0 = blockIdx.y * 32;
    const int tx = threadIdx.x & 31;
    const int ty = threadIdx.x >> 5;
    #pragma unroll
    for (int i = 0; i < 4; ++i) {
        const int r = ty + 8 * i;
        T[r][tx] = W[(size_t)(k0 + r) * CQ + c0 + tx];
    }
    __syncthreads();
    #pragma unroll
    for (int i = 0; i < 4; ++i) {
        const int r = ty + 8 * i;
        Wt[(size_t)(c0 + r) * K + k0 + tx] = __float2bfloat16(T[tx][r]);
    }
}

// ---------------------------------------------------------------------------
// fused_proj_k: LN fused directly into the projection A-tile (no qn/cn
// intermediates). 1024 blocks x 256 threads.
//   bid <  512: KV block — pool+LN 16 ctx rows -> LDS A(16x512 bf16,
//               XOR-swizzled) -> GEMM K=512, B-frags direct from L2-resident
//               Wkt/Wvt (no staging, no loop barriers). Writes Kb + permuted Vt.
//   bid >= 512: Q block — LN 16 query rows -> LDS A(16x256) -> GEMM K=256
//               vs Wqt, scaled by qsc. Writes Qb.
// ---------------------------------------------------------------------------
__global__ __launch_bounds__(256) void fused_proj_k(
    const float* __restrict__ query, const float* __restrict__ context,
    const __hip_bfloat16* __restrict__ Wqt, const __hip_bfloat16* __restrict__ Wkt,
    const __hip_bfloat16* __restrict__ Wvt,
    const float* __restrict__ bq, const float* __restrict__ bk,
    const float* __restrict__ bv,
    const float* __restrict__ gq, const float* __restrict__ betq,
    const float* __restrict__ gc, const float* __restrict__ betc,
    __hip_bfloat16* __restrict__ Qb, __hip_bfloat16* __restrict__ Kb,
    __hip_bfloat16* __restrict__ Vt, float qsc) {
    __shared__ __align__(16) unsigned short Asm[16 * 512];  // 16 KB A-tile
    __shared__ float Ss[64][16];
    __shared__ float S2s[64][16];
    __shared__ float Mu[16], Rs[16];

    const int bid = blockIdx.x;
    const int tid = threadIdx.x;
    const int wid = tid >> 6, lane = tid & 63;
    const int lg = lane >> 4, ln = lane & 15;

    if (bid < 512) {
        // ================= KV block =================
        const int n0t = bid & 63, b = bid >> 6;
        const int hq = n0t >> 1, wqh = (n0t & 1) * 16;
        const int n0 = n0t * 16;

        // ---- pool 2x2 + stats (register-resident, float4 loads)
        const int pp = tid & 7;          // position pair: local rows 2pp, 2pp+1
        const int cg = tid >> 3;         // channel group 0..31 (16 ch)
        const int ch0 = cg * 16;
        const float* Cb = context + ((size_t)b * CC + ch0) * 4096
                        + (size_t)(2 * hq) * 64 + (2 * wqh + 4 * pp);
        float pv0[16], pv1[16];
        float ss0 = 0.f, ss1 = 0.f, s20 = 0.f, s21 = 0.f;
        #pragma unroll
        for (int i = 0; i < 16; ++i) {
            const float4 r0 = *(const float4*)(Cb + (size_t)i * 4096);
            const float4 r1 = *(const float4*)(Cb + (size_t)i * 4096 + 64);
            const float v0 = (r0.x + r0.y + r1.x + r1.y) * 0.25f;
            const float v1 = (r0.z + r0.w + r1.z + r1.w) * 0.25f;
            pv0[i] = v0; pv1[i] = v1;
            ss0 += v0; s20 += v0 * v0;
            ss1 += v1; s21 += v1 * v1;
        }
        Ss[cg][2 * pp]      = ss0; S2s[cg][2 * pp]      = s20;
        Ss[cg][2 * pp + 1]  = ss1; S2s[cg][2 * pp + 1]  = s21;
        __syncthreads();
        if (tid < 16) {
            float ts = 0.f, t2 = 0.f;
            #pragma unroll
            for (int i = 0; i < 32; ++i) { ts += Ss[i][tid]; t2 += S2s[i][tid]; }
            const float mu  = ts * (1.f / CC);
            const float var = t2 * (1.f / CC) - mu * mu;
            Mu[tid] = mu; Rs[tid] = rsqrtf(var + 1e-5f);
        }
        __syncthreads();

        // ---- LN from regs -> XOR-swizzled LDS A[16][512]
        {
            const int lp0 = 2 * pp, lp1 = 2 * pp + 1;
            const float mu0 = Mu[lp0], rs0 = Rs[lp0];
            const float mu1 = Mu[lp1], rs1 = Rs[lp1];
            #pragma unroll
            for (int cc = 0; cc < 2; ++cc) {
                ushort8 o0, o1;
                #pragma unroll
                for (int e = 0; e < 8; ++e) {
                    const int ch = ch0 + 8 * cc + e;
                    o0[e] = f2bf((pv0[8 * cc + e] - mu0) * rs0 * gc[ch] + betc[ch]);
                    o1[e] = f2bf((pv1[8 * cc + e] - mu1) * rs1 * gc[ch] + betc[ch]);
                }
                const int ch8 = 2 * cg + cc;
                *(ushort8*)&Asm[lp0 * 512 + ((ch8 ^ (lp0 & 7)) * 8)] = o0;
                *(ushort8*)&Asm[lp1 * 512 + ((ch8 ^ (lp1 & 7)) * 8)] = o1;
            }
        }
        __syncthreads();

        // ---- GEMM K=512: A from LDS, B direct from global (L2-resident)
        const int isV = wid >> 1;
        const int wc0 = (wid & 1) * 128;
        const unsigned short* WtB = (const unsigned short*)(isV ? Wvt : Wkt);
        const float* bias = isV ? bv : bk;

        f32x4 acc[8] = {};
        #pragma unroll 4
        for (int t = 0; t < 16; ++t) {
            const int k0 = 32 * t;
            const int chunk = (4 * t + lg) ^ (ln & 7);
            const bf16x8 af = ldb8(&Asm[ln * 512 + chunk * 8]);
            #pragma unroll
            for (int j = 0; j < 8; ++j) {
                const bf16x8 wf = ldb8(WtB + (size_t)(wc0 + 16 * j + ln) * CC + k0 + 8 * lg);
                acc[j] = __builtin_amdgcn_mfma_f32_16x16x32_bf16(af, wf, acc[j], 0, 0, 0);
            }
        }

        // ---- epilogue
        #pragma unroll
        for (int j = 0; j < 8; ++j) {
            const int co = wc0 + 16 * j + ln;
            const int h = co >> 5, d = co & 31;
            const float bb = bias[co];
            if (!isV) {
                #pragma unroll
                for (int r = 0; r < 4; ++r)
                    Kb[(((size_t)b * NH + h) * N_ + n0 + 4 * lg + r) * HD + d] =
                        __float2bfloat16(acc[j][r] + bb);
            } else {
                const int gp = ((lg & 1) << 1) | (lg >> 1);  // pi: groups 1<->2
                ushort4v o;
                #pragma unroll
                for (int r = 0; r < 4; ++r) o[r] = f2bf(acc[j][r] + bb);
                *(ushort4v*)((unsigned short*)Vt
                    + (((size_t)b * NH + h) * HD + d) * N_ + n0 + 4 * gp) = o;
            }
        }
    } else {
        // ================= Q block =================
        const int u = bid - 512;
        const int n0t = u & 63, b = u >> 6;
        const int n0 = n0t * 16;

        // ---- LN(query): float4-along-n loads, register-resident
        const int n4 = tid & 3;          // n quad: rows 4n4..4n4+3
        const int cg = tid >> 2;         // channel group 0..63 (4 ch)
        const float* Qrow = query + ((size_t)b * CQ + 4 * cg) * N_ + n0 + 4 * n4;
        float qv[4][4];
        float sj[4] = {0.f, 0.f, 0.f, 0.f};
        float s2j[4] = {0.f, 0.f, 0.f, 0.f};
        #pragma unroll
        for (int i = 0; i < 4; ++i) {
            const float4 v = *(const float4*)(Qrow + (size_t)i * N_);
            qv[i][0] = v.x; qv[i][1] = v.y; qv[i][2] = v.z; qv[i][3] = v.w;
            sj[0] += v.x; s2j[0] += v.x * v.x;
            sj[1] += v.y; s2j[1] += v.y * v.y;
            sj[2] += v.z; s2j[2] += v.z * v.z;
            sj[3] += v.w; s2j[3] += v.w * v.w;
        }
        #pragma unroll
        for (int j = 0; j < 4; ++j) {
            Ss[cg][4 * n4 + j] = sj[j];
            S2s[cg][4 * n4 + j] = s2j[j];
        }
        __syncthreads();
        if (tid < 16) {
            float ts = 0.f, t2 = 0.f;
            #pragma unroll
            for (int i = 0; i < 64; ++i) { ts += Ss[i][tid]; t2 += S2s[i][tid]; }
            const float mu  = ts * (1.f / CQ);
            const float var = t2 * (1.f / CQ) - mu * mu;
            Mu[tid] = mu; Rs[tid] = rsqrtf(var + 1e-5f);
        }
        __syncthreads();
        #pragma unroll
        for (int j = 0; j < 4; ++j) {
            const int row = 4 * n4 + j;
            const float mu = Mu[row], rs = Rs[row];
            ushort4v o;
            #pragma unroll
            for (int i = 0; i < 4; ++i) {
                const int ch = 4 * cg + i;
                o[i] = f2bf((qv[i][j] - mu) * rs * gq[ch] + betq[ch]);
            }
            // 8B write into the XOR-swizzled 16B chunk (cg>>1), half cg&1
            *(ushort4v*)&Asm[row * 256 + (((cg >> 1) ^ (row & 7)) * 8) + (cg & 1) * 4] = o;
        }
        __syncthreads();

        // ---- GEMM K=256 vs Wqt (direct global B)
        const int wc0 = wid * 64;
        const unsigned short* WtB = (const unsigned short*)Wqt;
        f32x4 acc[4] = {};
        #pragma unroll 4
        for (int t = 0; t < 8; ++t) {
            const int k0 = 32 * t;
            const int chunk = (4 * t + lg) ^ (ln & 7);
            const bf16x8 af = ldb8(&Asm[ln * 256 + chunk * 8]);
            #pragma unroll
            for (int j = 0; j < 4; ++j) {
                const bf16x8 wf = ldb8(WtB + (size_t)(wc0 + 16 * j + ln) * CQ + k0 + 8 * lg);
                acc[j] = __builtin_amdgcn_mfma_f32_16x16x32_bf16(af, wf, acc[j], 0, 0, 0);
            }
        }
        #pragma unroll
        for (int j = 0; j < 4; ++j) {
            const int co = wc0 + 16 * j + ln;
            const int h = co >> 5, d = co & 31;
            const float bb = bq[co];
            #pragma unroll
            for (int r = 0; r < 4; ++r)
                Qb[(((size_t)b * NH + h) * N_ + n0 + 4 * lg + r) * HD + d] =
                    __float2bfloat16((acc[j][r] + bb) * qsc);
        }
    }
}

// ---------------------------------------------------------------------------
// 32x32 swapped-QK^T flash attention, in-register max-free softmax,
// software-pipelined K prefetch (2-deep) + top-of-step V loads.
// grid (16, 64) XCD-chunk-swizzled, block 256.
// ---------------------------------------------------------------------------
__global__ __launch_bounds__(256) void attn32_k(
    const __hip_bfloat16* __restrict__ Q,
    const __hip_bfloat16* __restrict__ K,
    const __hip_bfloat16* __restrict__ Vt,
    __hip_bfloat16* __restrict__ O) {
    __shared__ float accS[2][64][20];
    __shared__ float lwS[2][64];

    const int lin = blockIdx.x + 16 * blockIdx.y;
    const int eff = (lin & 7) * 128 + (lin >> 3);
    const int qt  = eff & 15;
    const int bh  = eff >> 4;
    const int b   = bh >> 3;
    const int h   = bh & 7;
    const int wid  = threadIdx.x >> 6;
    const int lane = threadIdx.x & 63;
    const int l31  = lane & 31;
    const int hh   = lane >> 5;
    const int qsub = wid >> 1;
    const int kvh  = wid & 1;
    const int q0   = qt * 64 + qsub * 32;

    const unsigned short* Qp = (const unsigned short*)Q + ((size_t)bh * N_ + q0) * HD;
    const unsigned short* Kbb = (const unsigned short*)K + (size_t)bh * N_ * HD;
    const unsigned short* Vb = (const unsigned short*)Vt + ((size_t)bh * HD + l31) * N_;

    bf16x8 qB[2];
    #pragma unroll
    for (int m = 0; m < 2; ++m)
        qB[m] = ldb8(Qp + (size_t)l31 * HD + 16 * m + 8 * hh);

    const f32x16 Z = {0.f,0.f,0.f,0.f,0.f,0.f,0.f,0.f,
                      0.f,0.f,0.f,0.f,0.f,0.f,0.f,0.f};
    f32x16 acc = Z;
    float ls0 = 0.f, ls1 = 0.f, ls2 = 0.f, ls3 = 0.f;

    const int kvbase = kvh * 512;
    const unsigned short* kp = Kbb + (size_t)(kvbase + l31) * HD + 8 * hh;
    const unsigned short* vp = Vb + kvbase + 8 * hh;

    bf16x8 kaA[2][4];
    #pragma unroll
    for (int j = 0; j < 4; ++j)
        kaA[0][j] = ldb8(kp + (j >> 1) * 1024 + (j & 1) * 16);

    #pragma unroll
    for (int st = 0; st < 8; ++st) {
        const int cur = st & 1;
        bf16x8 va[4];
        #pragma unroll
        for (int j = 0; j < 4; ++j)
            va[j] = ldb8(vp + st * 64 + 16 * j);
        if (st < 7) {
            const unsigned short* kp2 = kp + (size_t)(st + 1) * 2048;
            #pragma unroll
            for (int j = 0; j < 4; ++j)
                kaA[cur ^ 1][j] = ldb8(kp2 + (j >> 1) * 1024 + (j & 1) * 16);
        }

        f32x16 s0, s1;
        s0 = __builtin_amdgcn_mfma_f32_32x32x16_bf16(kaA[cur][0], qB[0], Z, 0, 0, 0);
        s0 = __builtin_amdgcn_mfma_f32_32x32x16_bf16(kaA[cur][1], qB[1], s0, 0, 0, 0);
        s1 = __builtin_amdgcn_mfma_f32_32x32x16_bf16(kaA[cur][2], qB[0], Z, 0, 0, 0);
        s1 = __builtin_amdgcn_mfma_f32_32x32x16_bf16(kaA[cur][3], qB[1], s1, 0, 0, 0);

        unsigned int pk[2][4][2];
        #pragma unroll
        for (int T = 0; T < 2; ++T) {
            float p[16];
            #pragma unroll
            for (int r = 0; r < 16; ++r)
                p[r] = __builtin_amdgcn_exp2f(T == 0 ? s0[r] : s1[r]);
            #pragma unroll
            for (int r = 0; r < 16; r += 4) {
                ls0 += p[r]; ls1 += p[r + 1]; ls2 += p[r + 2]; ls3 += p[r + 3];
            }
            #pragma unroll
            for (int c = 0; c < 4; ++c) {
                asm("v_cvt_pk_bf16_f32 %0, %1, %2"
                    : "=v"(pk[T][c][0]) : "v"(p[4 * c]), "v"(p[4 * c + 1]));
                asm("v_cvt_pk_bf16_f32 %0, %1, %2"
                    : "=v"(pk[T][c][1]) : "v"(p[4 * c + 2]), "v"(p[4 * c + 3]));
            }
        }

        #pragma unroll
        for (int w = 0; w < 4; ++w) {
            const int T = w >> 1, cp = w & 1;
            uint4v fu = {pk[T][2 * cp][0], pk[T][2 * cp][1],
                         pk[T][2 * cp + 1][0], pk[T][2 * cp + 1][1]};
            const bf16x8 pa = __builtin_bit_cast(bf16x8, fu);
            acc = __builtin_amdgcn_mfma_f32_32x32x16_bf16(pa, va[w], acc, 0, 0, 0);
        }
    }

    const float lsum = (ls0 + ls1) + (ls2 + ls3);
    const float lw = lsum + __shfl_xor(lsum, 32);

    if (kvh == 1) {
        #pragma unroll
        for (int r4 = 0; r4 < 4; ++r4) {
            float4 v = {acc[4 * r4], acc[4 * r4 + 1], acc[4 * r4 + 2], acc[4 * r4 + 3]};
            *(float4*)&accS[qsub][lane][4 * r4] = v;
        }
        lwS[qsub][lane] = lw;
    }
    __syncthreads();
    if (kvh == 0) {
        const float linv = 1.0f / (lw + lwS[qsub][lane]);
        #pragma unroll
        for (int r = 0; r < 16; ++r) {
            const int ql = (r & 3) + 8 * (r >> 2) + 4 * hh;
            const float vv = (acc[r] + accS[qsub][lane][r]) * __shfl(linv, ql);
            O[((size_t)b * N_ + q0 + ql) * CQ + h * HD + l31] = __float2bfloat16(vv);
        }
    }
}

// ---------------------------------------------------------------------------
// Output projection + bias + residual with reg-staged prefetch.
// grid (16, 4, B), block 256.
// ---------------------------------------------------------------------------
__global__ __launch_bounds__(256) void out_proj_k(const __hip_bfloat16* __restrict__ Ob,
                              const __hip_bfloat16* __restrict__ Wot,
                              const float* __restrict__ bo,
                              const float* __restrict__ query,
                              float* __restrict__ out) {
    __shared__ unsigned short As[64][40];
    __shared__ unsigned short Bs[64][40];
    const int b  = blockIdx.z;
    const int n0 = blockIdx.x * 64;
    const int c0 = blockIdx.y * 64;
    const int tid = threadIdx.x;
    const int wid = tid >> 6, lane = tid & 63;
    const int lg = lane >> 4, ln = lane & 15;
    const int wn0 = (wid & 1) * 32, wc0 = (wid >> 1) * 32;

    const unsigned short* Ab = (const unsigned short*)Ob + ((size_t)b * N_ + n0) * CQ;
    const unsigned short* Wb = (const unsigned short*)Wot + (size_t)c0 * CQ;
    const int sr = tid >> 2;
    const int sk = (tid & 3) * 8;

    f32x4 acc[2][2] = {};
    ushort8 ra = *(const ushort8*)(Ab + (size_t)sr * CQ + sk);
    ushort8 rw = *(const ushort8*)(Wb + (size_t)sr * CQ + sk);

    for (int t = 0; t < 8; ++t) {
        *(ushort8*)&As[sr][sk] = ra;
        *(ushort8*)&Bs[sr][sk] = rw;
        __syncthreads();
        if (t < 7) {
            ra = *(const ushort8*)(Ab + (size_t)sr * CQ + (t + 1) * 32 + sk);
            rw = *(const ushort8*)(Wb + (size_t)sr * CQ + (t + 1) * 32 + sk);
        }
        bf16x8 a[2], w[2];
        #pragma unroll
        for (int i = 0; i < 2; ++i)
            a[i] = ldb8(&As[wn0 + 16 * i + ln][8 * lg]);
        #pragma unroll
        for (int j = 0; j < 2; ++j)
            w[j] = ldb8(&Bs[wc0 + 16 * j + ln][8 * lg]);
        #pragma unroll
        for (int i = 0; i < 2; ++i)
            #pragma unroll
            for (int j = 0; j < 2; ++j)
                acc[i][j] = __builtin_amdgcn_mfma_f32_16x16x32_bf16(a[i], w[j], acc[i][j], 0, 0, 0);
        __syncthreads();
    }

    #pragma unroll
    for (int j = 0; j < 2; ++j) {
        const int co = c0 + wc0 + 16 * j + ln;
        const float bb = bo[co];
        #pragma unroll
        for (int i = 0; i < 2; ++i) {
            const int nb = n0 + wn0 + 16 * i + 4 * lg;
            const float4 res = *(const float4*)&query[((size_t)b * CQ + co) * N_ + nb];
            float4 o;
            o.x = acc[i][j][0] + bb + res.x;
            o.y = acc[i][j][1] + bb + res.y;
            o.z = acc[i][j][2] + bb + res.z;
            o.w = acc[i][j][3] + bb + res.w;
            *(float4*)&out[((size_t)b * CQ + co) * N_ + nb] = o;
        }
    }
}

// ---------------------------------------------------------------------------
extern "C" void kernel_launch(void* const* d_in, const int* in_sizes, int n_in,
                              void* d_out, int out_size, void* d_ws, size_t ws_size,
                              hipStream_t stream) {
    const float* query   = (const float*)d_in[0];
    const float* context = (const float*)d_in[1];
    const float* Wq = (const float*)d_in[2];
    const float* bq = (const float*)d_in[3];
    const float* Wk = (const float*)d_in[4];
    const float* bk = (const float*)d_in[5];
    const float* Wv = (const float*)d_in[6];
    const float* bv = (const float*)d_in[7];
    const float* Wo = (const float*)d_in[8];
    const float* bo = (const float*)d_in[9];
    const float* gq   = (const float*)d_in[10];
    const float* betq = (const float*)d_in[11];
    const float* gc   = (const float*)d_in[12];
    const float* betc = (const float*)d_in[13];
    float* out = (float*)d_out;

    char* w = (char*)d_ws;
    __hip_bfloat16* Qb  = (__hip_bfloat16*)w;  w += (size_t)B_ * NH * N_ * HD * 2;
    __hip_bfloat16* Kb  = (__hip_bfloat16*)w;  w += (size_t)B_ * NH * N_ * HD * 2;
    __hip_bfloat16* Vt  = (__hip_bfloat16*)w;  w += (size_t)B_ * NH * HD * N_ * 2;
    __hip_bfloat16* Ob  = (__hip_bfloat16*)w;  w += (size_t)B_ * N_ * CQ * 2;
    __hip_bfloat16* Wqt = (__hip_bfloat16*)w;  w += (size_t)CQ * CQ * 2;
    __hip_bfloat16* Wkt = (__hip_bfloat16*)w;  w += (size_t)CQ * CC * 2;
    __hip_bfloat16* Wvt = (__hip_bfloat16*)w;  w += (size_t)CQ * CC * 2;
    __hip_bfloat16* Wot = (__hip_bfloat16*)w;  w += (size_t)CQ * CQ * 2;

    wt_conv_all_k<<<dim3(16, 8, 4), 256, 0, stream>>>(Wq, Wk, Wv, Wo,
                                                      Wqt, Wkt, Wvt, Wot);

    // scale includes log2(e) so the softmax exp becomes a bare v_exp_f32
    const float qsc = 0.17677669529663687f * 1.4426950408889634f;
    fused_proj_k<<<dim3(1024), 256, 0, stream>>>(query, context,
                                                 Wqt, Wkt, Wvt,
                                                 bq, bk, bv,
                                                 gq, betq, gc, betc,
                                                 Qb, Kb, Vt, qsc);

    attn32_k<<<dim3(16, 64), 256, 0, stream>>>(Qb, Kb, Vt, Ob);

    out_proj_k<<<dim3(16, 4, 8), 256, 0, stream>>>(Ob, Wot, bo, query, out);
}

// Round 11
// 76.726 us; speedup vs baseline: 1.2416x; 1.2416x over previous
//
#include <hip/hip_runtime.h>
#include <hip/hip_bf16.h>
#include <cstddef>

#define B_  8
#define CQ  256
#define CC  512
#define N_  1024   // Hq*Wq
#define HQ  32
#define WQ  32
#define NH  8
#define HD  32

typedef __bf16 bf16x8 __attribute__((ext_vector_type(8)));
typedef float f32x4 __attribute__((ext_vector_type(4)));
typedef float f32x16 __attribute__((ext_vector_type(16)));
typedef unsigned int uint4v __attribute__((ext_vector_type(4)));
typedef unsigned short ushort8 __attribute__((ext_vector_type(8)));
typedef unsigned short ushort4v __attribute__((ext_vector_type(4)));

__device__ __forceinline__ unsigned short f2bf(float x) {
    return __builtin_bit_cast(unsigned short, __float2bfloat16(x));
}
__device__ __forceinline__ bf16x8 ldb8(const unsigned short* p) {
    return __builtin_bit_cast(bf16x8, *(const ushort8*)p);
}

// ---------------------------------------------------------------------------
// prep_k: ALL preprocessing in ONE launch (1664 blocks x 256).
//   [0,512):     weight transpose f32->bf16 (4 matrices)
//   [512,1536):  pool+LN(context) -> cn (B,N,Cc) bf16 [float4, reg-resident,
//                1024 blocks x 8 positions — halved per-thread chain vs R9]
//   [1536,1664): LN(query) -> qn (B,N,Cq) bf16 [float4-along-n, reg-resident]
// ---------------------------------------------------------------------------
__global__ __launch_bounds__(256) void prep_k(
    const float* __restrict__ query, const float* __restrict__ context,
    const float* __restrict__ Wq, const float* __restrict__ Wk,
    const float* __restrict__ Wv, const float* __restrict__ Wo,
    const float* __restrict__ gq, const float* __restrict__ betq,
    const float* __restrict__ gc, const float* __restrict__ betc,
    __hip_bfloat16* __restrict__ Wqt, __hip_bfloat16* __restrict__ Wkt,
    __hip_bfloat16* __restrict__ Wvt, __hip_bfloat16* __restrict__ Wot,
    __hip_bfloat16* __restrict__ qn, __hip_bfloat16* __restrict__ cn) {
    __shared__ float T[32][33];         // weight transpose tile
    __shared__ float SsA[64][16];       // ctx stats partials (cols 0..7 used)
    __shared__ float S2A[64][16];
    __shared__ float SsB[16][64];       // query stats partials
    __shared__ float S2B[16][64];
    __shared__ float Mu[64], Rs[64];

    const int bid = blockIdx.x;
    const int tid = threadIdx.x;

    if (bid < 512) {
        // ---------------- weight transpose ----------------
        const int x = bid & 15, y = (bid >> 4) & 7, z = bid >> 7;
        const float* W; __hip_bfloat16* Wt; int K;
        switch (z) {
            case 0: W = Wq; Wt = Wqt; K = CQ; break;
            case 1: W = Wk; Wt = Wkt; K = CC; break;
            case 2: W = Wv; Wt = Wvt; K = CC; break;
            default: W = Wo; Wt = Wot; K = CQ; break;
        }
        const int k0 = x * 32;
        if (k0 >= K) return;
        const int c0 = y * 32;
        const int tx = tid & 31, ty = tid >> 5;
        #pragma unroll
        for (int i = 0; i < 4; ++i) {
            const int r = ty + 8 * i;
            T[r][tx] = W[(size_t)(k0 + r) * CQ + c0 + tx];
        }
        __syncthreads();
        #pragma unroll
        for (int i = 0; i < 4; ++i) {
            const int r = ty + 8 * i;
            Wt[(size_t)(c0 + r) * K + k0 + tx] = __float2bfloat16(T[tx][r]);
        }
    } else if (bid < 1536) {
        // ------- pool + LN(context): 1024 blocks, 8 positions each -------
        const int u   = bid - 512;
        const int wq8 = u & 3, hq = (u >> 2) & 31, b = u >> 7;
        const int pp  = tid & 3;          // position pair: 2pp, 2pp+1 (of 8)
        const int cg  = tid >> 2;         // channel group 0..63 (8 ch each)
        const int ch0 = cg * 8;

        const float* Cb = context + ((size_t)b * CC + ch0) * 4096
                        + (size_t)(2 * hq) * 64 + (16 * wq8 + 4 * pp);
        float pv0[8], pv1[8];
        float ss0 = 0.f, ss1 = 0.f, s20 = 0.f, s21 = 0.f;
        #pragma unroll
        for (int i = 0; i < 8; ++i) {
            const float4 r0 = *(const float4*)(Cb + (size_t)i * 4096);
            const float4 r1 = *(const float4*)(Cb + (size_t)i * 4096 + 64);
            const float v0 = (r0.x + r0.y + r1.x + r1.y) * 0.25f;
            const float v1 = (r0.z + r0.w + r1.z + r1.w) * 0.25f;
            pv0[i] = v0; pv1[i] = v1;
            ss0 += v0; s20 += v0 * v0;
            ss1 += v1; s21 += v1 * v1;
        }
        SsA[cg][2 * pp]     = ss0; S2A[cg][2 * pp]     = s20;
        SsA[cg][2 * pp + 1] = ss1; S2A[cg][2 * pp + 1] = s21;
        __syncthreads();
        if (tid < 8) {
            float ts = 0.f, t2 = 0.f;
            #pragma unroll
            for (int i = 0; i < 64; ++i) { ts += SsA[i][tid]; t2 += S2A[i][tid]; }
            const float mu  = ts * (1.f / CC);
            const float var = t2 * (1.f / CC) - mu * mu;
            Mu[tid] = mu; Rs[tid] = rsqrtf(var + 1e-5f);
        }
        __syncthreads();
        const float mu0 = Mu[2 * pp],     rs0 = Rs[2 * pp];
        const float mu1 = Mu[2 * pp + 1], rs1 = Rs[2 * pp + 1];
        const int pos = hq * 32 + wq8 * 8 + 2 * pp;
        unsigned short* dst = (unsigned short*)cn
            + ((size_t)b * N_ + pos) * CC + ch0;
        ushort8 o0, o1;
        #pragma unroll
        for (int e = 0; e < 8; ++e) {
            o0[e] = f2bf((pv0[e] - mu0) * rs0 * gc[ch0 + e] + betc[ch0 + e]);
            o1[e] = f2bf((pv1[e] - mu1) * rs1 * gc[ch0 + e] + betc[ch0 + e]);
        }
        *(ushort8*)(dst)      = o0;
        *(ushort8*)(dst + CC) = o1;
    } else {
        // --------- LN(query): float4-along-n loads, register-resident ---------
        const int u  = bid - 1536;
        const int nt = u & 15, b = u >> 4;
        const int nq = tid & 15;          // n-quad: positions 4nq..4nq+3
        const int cg = tid >> 4;          // channel group 0..15 (16 ch each)
        const int ch0 = cg * 16;
        const int nb  = nt * 64 + 4 * nq;

        const float* Qb = query + ((size_t)b * CQ + ch0) * N_ + nb;
        float qv[64];
        float ps[4] = {0.f, 0.f, 0.f, 0.f};
        float p2[4] = {0.f, 0.f, 0.f, 0.f};
        #pragma unroll
        for (int i = 0; i < 16; ++i) {
            const float4 v = *(const float4*)(Qb + (size_t)i * N_);
            qv[4 * i + 0] = v.x; qv[4 * i + 1] = v.y;
            qv[4 * i + 2] = v.z; qv[4 * i + 3] = v.w;
            ps[0] += v.x; p2[0] += v.x * v.x;
            ps[1] += v.y; p2[1] += v.y * v.y;
            ps[2] += v.z; p2[2] += v.z * v.z;
            ps[3] += v.w; p2[3] += v.w * v.w;
        }
        #pragma unroll
        for (int j = 0; j < 4; ++j) {
            SsB[cg][4 * nq + j] = ps[j];
            S2B[cg][4 * nq + j] = p2[j];
        }
        __syncthreads();
        if (tid < 64) {
            float ts = 0.f, t2 = 0.f;
            #pragma unroll
            for (int i = 0; i < 16; ++i) { ts += SsB[i][tid]; t2 += S2B[i][tid]; }
            const float mu  = ts * (1.f / CQ);
            const float var = t2 * (1.f / CQ) - mu * mu;
            Mu[tid] = mu; Rs[tid] = rsqrtf(var + 1e-5f);
        }
        __syncthreads();
        #pragma unroll
        for (int j = 0; j < 4; ++j) {
            const float mu = Mu[4 * nq + j], rs = Rs[4 * nq + j];
            ushort8 o0, o1;
            #pragma unroll
            for (int i = 0; i < 8; ++i)
                o0[i] = f2bf((qv[4 * i + j] - mu) * rs * gq[ch0 + i] + betq[ch0 + i]);
            #pragma unroll
            for (int i = 0; i < 8; ++i)
                o1[i] = f2bf((qv[4 * (8 + i) + j] - mu) * rs * gq[ch0 + 8 + i] + betq[ch0 + 8 + i]);
            unsigned short* dst = (unsigned short*)qn
                + ((size_t)b * N_ + nb + j) * CQ + ch0;
            *(ushort8*)(dst)     = o0;
            *(ushort8*)(dst + 8) = o1;
        }
    }
}

// ---------------------------------------------------------------------------
// proj_all_k: Q projection (z>=8) and fused K+V projection (z<8) in one
// launch, reg-staged global prefetch. V columns written PERMUTED per
// 16-block (groups-of-4 1<->2 swap) so attention reads contiguous PV B-frags.
// grid (16, 4, 16), block 256.  [unchanged from R9]
// ---------------------------------------------------------------------------
__global__ __launch_bounds__(256) void proj_all_k(
    const __hip_bfloat16* __restrict__ qn, const __hip_bfloat16* __restrict__ cn,
    const __hip_bfloat16* __restrict__ Wqt, const __hip_bfloat16* __restrict__ Wkt,
    const __hip_bfloat16* __restrict__ Wvt,
    const float* __restrict__ bq, const float* __restrict__ bk,
    const float* __restrict__ bv,
    __hip_bfloat16* __restrict__ Qb, __hip_bfloat16* __restrict__ Kb,
    __hip_bfloat16* __restrict__ Vt, float qsc) {
    __shared__ unsigned short As[64][40];
    __shared__ unsigned short B1[64][40];
    __shared__ unsigned short B2[64][40];

    const int zz = blockIdx.z;
    const int n0 = blockIdx.x * 64;
    const int c0 = blockIdx.y * 64;
    const int tid = threadIdx.x;
    const int wid = tid >> 6, lane = tid & 63;
    const int lg = lane >> 4, ln = lane & 15;
    const int wn0 = (wid & 1) * 32, wc0 = (wid >> 1) * 32;
    const int sr = tid >> 2;
    const int sk = (tid & 3) * 8;

    if (zz >= 8) {
        // ---------------- Q projection (K = 256) ----------------
        const int b = zz - 8;
        const unsigned short* Ab = (const unsigned short*)qn + ((size_t)b * N_ + n0) * CQ;
        const unsigned short* Wb = (const unsigned short*)Wqt + (size_t)c0 * CQ;
        f32x4 acc[2][2] = {};
        ushort8 ra = *(const ushort8*)(Ab + (size_t)sr * CQ + sk);
        ushort8 rw = *(const ushort8*)(Wb + (size_t)sr * CQ + sk);
        for (int t = 0; t < 8; ++t) {
            *(ushort8*)&As[sr][sk] = ra;
            *(ushort8*)&B1[sr][sk] = rw;
            __syncthreads();
            if (t < 7) {
                ra = *(const ushort8*)(Ab + (size_t)sr * CQ + (t + 1) * 32 + sk);
                rw = *(const ushort8*)(Wb + (size_t)sr * CQ + (t + 1) * 32 + sk);
            }
            bf16x8 a[2], w[2];
            #pragma unroll
            for (int i = 0; i < 2; ++i) a[i] = ldb8(&As[wn0 + 16 * i + ln][8 * lg]);
            #pragma unroll
            for (int j = 0; j < 2; ++j) w[j] = ldb8(&B1[wc0 + 16 * j + ln][8 * lg]);
            #pragma unroll
            for (int i = 0; i < 2; ++i)
                #pragma unroll
                for (int j = 0; j < 2; ++j)
                    acc[i][j] = __builtin_amdgcn_mfma_f32_16x16x32_bf16(a[i], w[j], acc[i][j], 0, 0, 0);
            __syncthreads();
        }
        #pragma unroll
        for (int j = 0; j < 2; ++j) {
            const int co = c0 + wc0 + 16 * j + ln;
            const int h = co >> 5, d = co & 31;
            const float bb = bq[co];
            #pragma unroll
            for (int i = 0; i < 2; ++i)
                #pragma unroll
                for (int r = 0; r < 4; ++r) {
                    const int n = n0 + wn0 + 16 * i + 4 * lg + r;
                    Qb[(((size_t)b * NH + h) * N_ + n) * HD + d] =
                        __float2bfloat16((acc[i][j][r] + bb) * qsc);
                }
        }
    } else {
        // ---------------- K + V projection (K = 512) ----------------
        const int b = zz;
        const unsigned short* Ab  = (const unsigned short*)cn + ((size_t)b * N_ + n0) * CC;
        const unsigned short* Wkb = (const unsigned short*)Wkt + (size_t)c0 * CC;
        const unsigned short* Wvb = (const unsigned short*)Wvt + (size_t)c0 * CC;
        f32x4 accK[2][2] = {};
        f32x4 accV[2][2] = {};
        ushort8 ra = *(const ushort8*)(Ab  + (size_t)sr * CC + sk);
        ushort8 rk = *(const ushort8*)(Wkb + (size_t)sr * CC + sk);
        ushort8 rv = *(const ushort8*)(Wvb + (size_t)sr * CC + sk);
        for (int t = 0; t < 16; ++t) {
            *(ushort8*)&As[sr][sk] = ra;
            *(ushort8*)&B1[sr][sk] = rk;
            *(ushort8*)&B2[sr][sk] = rv;
            __syncthreads();
            if (t < 15) {
                ra = *(const ushort8*)(Ab  + (size_t)sr * CC + (t + 1) * 32 + sk);
                rk = *(const ushort8*)(Wkb + (size_t)sr * CC + (t + 1) * 32 + sk);
                rv = *(const ushort8*)(Wvb + (size_t)sr * CC + (t + 1) * 32 + sk);
            }
            bf16x8 a[2], wk[2], wv[2];
            #pragma unroll
            for (int i = 0; i < 2; ++i) {
                a[i]  = ldb8(&As[wn0 + 16 * i + ln][8 * lg]);
                wk[i] = ldb8(&B1[wc0 + 16 * i + ln][8 * lg]);
                wv[i] = ldb8(&B2[wc0 + 16 * i + ln][8 * lg]);
            }
            #pragma unroll
            for (int i = 0; i < 2; ++i)
                #pragma unroll
                for (int j = 0; j < 2; ++j) {
                    accK[i][j] = __builtin_amdgcn_mfma_f32_16x16x32_bf16(a[i], wk[j], accK[i][j], 0, 0, 0);
                    accV[i][j] = __builtin_amdgcn_mfma_f32_16x16x32_bf16(a[i], wv[j], accV[i][j], 0, 0, 0);
                }
            __syncthreads();
        }
        #pragma unroll
        for (int j = 0; j < 2; ++j) {
            const int co = c0 + wc0 + 16 * j + ln;
            const int h = co >> 5, d = co & 31;
            const float bbk = bk[co], bbv = bv[co];
            #pragma unroll
            for (int i = 0; i < 2; ++i) {
                const int nb = n0 + wn0 + 16 * i + 4 * lg;
                #pragma unroll
                for (int r = 0; r < 4; ++r)
                    Kb[(((size_t)b * NH + h) * N_ + nb + r) * HD + d] =
                        __float2bfloat16(accK[i][j][r] + bbk);
                ushort4v o;
                #pragma unroll
                for (int r = 0; r < 4; ++r) o[r] = f2bf(accV[i][j][r] + bbv);
                // permuted column write: 4-groups 1<->2 swap within 16-block
                const int g  = (nb >> 2) & 3;
                const int gp = ((g & 1) << 1) | (g >> 1);
                const int nbp = (nb & ~15) | (gp << 2);
                *(ushort4v*)((unsigned short*)Vt + (((size_t)b * NH + h) * HD + d) * N_ + nbp) = o;
            }
        }
    }
}

// ---------------------------------------------------------------------------
// 32x32 swapped-QK^T flash attention, in-register max-free softmax,
// 4-way kv-split: block = one 32-row q-subtile, 4 waves = 4 kv-quarters.
// 2-deep K prefetch + top-of-step V loads. grid (32, 64) XCD-swizzled.
// ---------------------------------------------------------------------------
__global__ __launch_bounds__(256) void attn32_k(
    const __hip_bfloat16* __restrict__ Q,
    const __hip_bfloat16* __restrict__ K,
    const __hip_bfloat16* __restrict__ Vt,
    __hip_bfloat16* __restrict__ O) {
    __shared__ float accS[3][64][20];
    __shared__ float lwS[3][64];

    const int lin = blockIdx.x + 32 * blockIdx.y;
    const int eff = (lin & 7) * 256 + (lin >> 3);   // 2048 blocks, 8 XCDs
    const int qt  = eff & 31;
    const int bh  = eff >> 5;
    const int b   = bh >> 3;
    const int h   = bh & 7;
    const int wid  = threadIdx.x >> 6;   // kv quarter 0..3
    const int lane = threadIdx.x & 63;
    const int l31  = lane & 31;
    const int hh   = lane >> 5;
    const int q0   = qt * 32;

    const unsigned short* Qp = (const unsigned short*)Q + ((size_t)bh * N_ + q0) * HD;
    const unsigned short* Kbb = (const unsigned short*)K + (size_t)bh * N_ * HD;
    const unsigned short* Vb = (const unsigned short*)Vt + ((size_t)bh * HD + l31) * N_;

    bf16x8 qB[2];
    #pragma unroll
    for (int m = 0; m < 2; ++m)
        qB[m] = ldb8(Qp + (size_t)l31 * HD + 16 * m + 8 * hh);

    const f32x16 Z = {0.f,0.f,0.f,0.f,0.f,0.f,0.f,0.f,
                      0.f,0.f,0.f,0.f,0.f,0.f,0.f,0.f};
    f32x16 acc = Z;
    float ls0 = 0.f, ls1 = 0.f, ls2 = 0.f, ls3 = 0.f;

    const int kvbase = wid * 256;
    const unsigned short* kp = Kbb + (size_t)(kvbase + l31) * HD + 8 * hh;
    const unsigned short* vp = Vb + kvbase + 8 * hh;

    bf16x8 kaA[2][4];
    #pragma unroll
    for (int j = 0; j < 4; ++j)
        kaA[0][j] = ldb8(kp + (j >> 1) * 1024 + (j & 1) * 16);

    #pragma unroll
    for (int st = 0; st < 4; ++st) {
        const int cur = st & 1;
        bf16x8 va[4];
        #pragma unroll
        for (int j = 0; j < 4; ++j)
            va[j] = ldb8(vp + st * 64 + 16 * j);
        if (st < 3) {
            const unsigned short* kp2 = kp + (size_t)(st + 1) * 2048;
            #pragma unroll
            for (int j = 0; j < 4; ++j)
                kaA[cur ^ 1][j] = ldb8(kp2 + (j >> 1) * 1024 + (j & 1) * 16);
        }

        f32x16 s0, s1;
        s0 = __builtin_amdgcn_mfma_f32_32x32x16_bf16(kaA[cur][0], qB[0], Z, 0, 0, 0);
        s0 = __builtin_amdgcn_mfma_f32_32x32x16_bf16(kaA[cur][1], qB[1], s0, 0, 0, 0);
        s1 = __builtin_amdgcn_mfma_f32_32x32x16_bf16(kaA[cur][2], qB[0], Z, 0, 0, 0);
        s1 = __builtin_amdgcn_mfma_f32_32x32x16_bf16(kaA[cur][3], qB[1], s1, 0, 0, 0);

        unsigned int pk[2][4][2];
        #pragma unroll
        for (int T = 0; T < 2; ++T) {
            float p[16];
            #pragma unroll
            for (int r = 0; r < 16; ++r)
                p[r] = __builtin_amdgcn_exp2f(T == 0 ? s0[r] : s1[r]);
            #pragma unroll
            for (int r = 0; r < 16; r += 4) {
                ls0 += p[r]; ls1 += p[r + 1]; ls2 += p[r + 2]; ls3 += p[r + 3];
            }
            #pragma unroll
            for (int c = 0; c < 4; ++c) {
                asm("v_cvt_pk_bf16_f32 %0, %1, %2"
                    : "=v"(pk[T][c][0]) : "v"(p[4 * c]), "v"(p[4 * c + 1]));
                asm("v_cvt_pk_bf16_f32 %0, %1, %2"
                    : "=v"(pk[T][c][1]) : "v"(p[4 * c + 2]), "v"(p[4 * c + 3]));
            }
        }

        #pragma unroll
        for (int w = 0; w < 4; ++w) {
            const int T = w >> 1, cp = w & 1;
            uint4v fu = {pk[T][2 * cp][0], pk[T][2 * cp][1],
                         pk[T][2 * cp + 1][0], pk[T][2 * cp + 1][1]};
            const bf16x8 pa = __builtin_bit_cast(bf16x8, fu);
            acc = __builtin_amdgcn_mfma_f32_32x32x16_bf16(pa, va[w], acc, 0, 0, 0);
        }
    }

    const float lsum = (ls0 + ls1) + (ls2 + ls3);
    const float lw = lsum + __shfl_xor(lsum, 32);

    if (wid > 0) {
        #pragma unroll
        for (int r4 = 0; r4 < 4; ++r4) {
            float4 v = {acc[4 * r4], acc[4 * r4 + 1], acc[4 * r4 + 2], acc[4 * r4 + 3]};
            *(float4*)&accS[wid - 1][lane][4 * r4] = v;
        }
        lwS[wid - 1][lane] = lw;
    }
    __syncthreads();
    if (wid == 0) {
        const float ltot = lw + lwS[0][lane] + lwS[1][lane] + lwS[2][lane];
        const float linv = 1.0f / ltot;
        #pragma unroll
        for (int r = 0; r < 16; ++r) {
            const int ql = (r & 3) + 8 * (r >> 2) + 4 * hh;
            const float vv = (acc[r] + accS[0][lane][r] + accS[1][lane][r]
                              + accS[2][lane][r]) * __shfl(linv, ql);
            O[((size_t)b * N_ + q0 + ql) * CQ + h * HD + l31] = __float2bfloat16(vv);
        }
    }
}

// ---------------------------------------------------------------------------
// Output projection + bias + residual with reg-staged prefetch.
// grid (16, 4, B), block 256.  [unchanged from R9]
// ---------------------------------------------------------------------------
__global__ __launch_bounds__(256) void out_proj_k(const __hip_bfloat16* __restrict__ Ob,
                              const __hip_bfloat16* __restrict__ Wot,
                              const float* __restrict__ bo,
                              const float* __restrict__ query,
                              float* __restrict__ out) {
    __shared__ unsigned short As[64][40];
    __shared__ unsigned short Bs[64][40];
    const int b  = blockIdx.z;
    const int n0 = blockIdx.x * 64;
    const int c0 = blockIdx.y * 64;
    const int tid = threadIdx.x;
    const int wid = tid >> 6, lane = tid & 63;
    const int lg = lane >> 4, ln = lane & 15;
    const int wn0 = (wid & 1) * 32, wc0 = (wid >> 1) * 32;

    const unsigned short* Ab = (const unsigned short*)Ob + ((size_t)b * N_ + n0) * CQ;
    const unsigned short* Wb = (const unsigned short*)Wot + (size_t)c0 * CQ;
    const int sr = tid >> 2;
    const int sk = (tid & 3) * 8;

    f32x4 acc[2][2] = {};
    ushort8 ra = *(const ushort8*)(Ab + (size_t)sr * CQ + sk);
    ushort8 rw = *(const ushort8*)(Wb + (size_t)sr * CQ + sk);

    for (int t = 0; t < 8; ++t) {
        *(ushort8*)&As[sr][sk] = ra;
        *(ushort8*)&Bs[sr][sk] = rw;
        __syncthreads();
        if (t < 7) {
            ra = *(const ushort8*)(Ab + (size_t)sr * CQ + (t + 1) * 32 + sk);
            rw = *(const ushort8*)(Wb + (size_t)sr * CQ + (t + 1) * 32 + sk);
        }
        bf16x8 a[2], w[2];
        #pragma unroll
        for (int i = 0; i < 2; ++i)
            a[i] = ldb8(&As[wn0 + 16 * i + ln][8 * lg]);
        #pragma unroll
        for (int j = 0; j < 2; ++j)
            w[j] = ldb8(&Bs[wc0 + 16 * j + ln][8 * lg]);
        #pragma unroll
        for (int i = 0; i < 2; ++i)
            #pragma unroll
            for (int j = 0; j < 2; ++j)
                acc[i][j] = __builtin_amdgcn_mfma_f32_16x16x32_bf16(a[i], w[j], acc[i][j], 0, 0, 0);
        __syncthreads();
    }

    #pragma unroll
    for (int j = 0; j < 2; ++j) {
        const int co = c0 + wc0 + 16 * j + ln;
        const float bb = bo[co];
        #pragma unroll
        for (int i = 0; i < 2; ++i) {
            const int nb = n0 + wn0 + 16 * i + 4 * lg;
            const float4 res = *(const float4*)&query[((size_t)b * CQ + co) * N_ + nb];
            float4 o;
            o.x = acc[i][j][0] + bb + res.x;
            o.y = acc[i][j][1] + bb + res.y;
            o.z = acc[i][j][2] + bb + res.z;
            o.w = acc[i][j][3] + bb + res.w;
            *(float4*)&out[((size_t)b * CQ + co) * N_ + nb] = o;
        }
    }
}

// ---------------------------------------------------------------------------
extern "C" void kernel_launch(void* const* d_in, const int* in_sizes, int n_in,
                              void* d_out, int out_size, void* d_ws, size_t ws_size,
                              hipStream_t stream) {
    const float* query   = (const float*)d_in[0];
    const float* context = (const float*)d_in[1];
    const float* Wq = (const float*)d_in[2];
    const float* bq = (const float*)d_in[3];
    const float* Wk = (const float*)d_in[4];
    const float* bk = (const float*)d_in[5];
    const float* Wv = (const float*)d_in[6];
    const float* bv = (const float*)d_in[7];
    const float* Wo = (const float*)d_in[8];
    const float* bo = (const float*)d_in[9];
    const float* gq   = (const float*)d_in[10];
    const float* betq = (const float*)d_in[11];
    const float* gc   = (const float*)d_in[12];
    const float* betc = (const float*)d_in[13];
    float* out = (float*)d_out;

    char* w = (char*)d_ws;
    __hip_bfloat16* qn  = (__hip_bfloat16*)w;  w += (size_t)B_ * N_ * CQ * 2;
    __hip_bfloat16* cn  = (__hip_bfloat16*)w;  w += (size_t)B_ * N_ * CC * 2;
    __hip_bfloat16* Qb  = (__hip_bfloat16*)w;  w += (size_t)B_ * NH * N_ * HD * 2;
    __hip_bfloat16* Kb  = (__hip_bfloat16*)w;  w += (size_t)B_ * NH * N_ * HD * 2;
    __hip_bfloat16* Vt  = (__hip_bfloat16*)w;  w += (size_t)B_ * NH * HD * N_ * 2;
    __hip_bfloat16* Ob  = (__hip_bfloat16*)w;  w += (size_t)B_ * N_ * CQ * 2;
    __hip_bfloat16* Wqt = (__hip_bfloat16*)w;  w += (size_t)CQ * CQ * 2;
    __hip_bfloat16* Wkt = (__hip_bfloat16*)w;  w += (size_t)CQ * CC * 2;
    __hip_bfloat16* Wvt = (__hip_bfloat16*)w;  w += (size_t)CQ * CC * 2;
    __hip_bfloat16* Wot = (__hip_bfloat16*)w;  w += (size_t)CQ * CQ * 2;

    prep_k<<<dim3(1664), 256, 0, stream>>>(query, context, Wq, Wk, Wv, Wo,
                                           gq, betq, gc, betc,
                                           Wqt, Wkt, Wvt, Wot, qn, cn);

    // scale includes log2(e) so the softmax exp becomes a bare v_exp_f32
    const float qsc = 0.17677669529663687f * 1.4426950408889634f;
    proj_all_k<<<dim3(16, 4, 16), 256, 0, stream>>>(qn, cn, Wqt, Wkt, Wvt,
                                                    bq, bk, bv, Qb, Kb, Vt, qsc);

    attn32_k<<<dim3(32, 64), 256, 0, stream>>>(Qb, Kb, Vt, Ob);

    out_proj_k<<<dim3(16, 4, 8), 256, 0, stream>>>(Ob, Wot, bo, query, out);
}

// Round 12
// 67.257 us; speedup vs baseline: 1.4164x; 1.1408x over previous
//
#include <hip/hip_runtime.h>
#include <hip/hip_bf16.h>
#include <cstddef>

#define B_  8
#define CQ  256
#define CC  512
#define N_  1024   // Hq*Wq
#define HQ  32
#define WQ  32
#define NH  8
#define HD  32

typedef __bf16 bf16x8 __attribute__((ext_vector_type(8)));
typedef float f32x4 __attribute__((ext_vector_type(4)));
typedef float f32x16 __attribute__((ext_vector_type(16)));
typedef unsigned int uint4v __attribute__((ext_vector_type(4)));
typedef unsigned short ushort8 __attribute__((ext_vector_type(8)));
typedef unsigned short ushort4v __attribute__((ext_vector_type(4)));

__device__ __forceinline__ unsigned short f2bf(float x) {
    return __builtin_bit_cast(unsigned short, __float2bfloat16(x));
}
__device__ __forceinline__ bf16x8 ldb8(const unsigned short* p) {
    return __builtin_bit_cast(bf16x8, *(const ushort8*)p);
}

// ---------------------------------------------------------------------------
// prep_k: ALL preprocessing in ONE launch (1152 blocks x 256).  [R9-exact]
//   [0,512):     weight transpose f32->bf16 (4 matrices)
//   [512,1024):  pool+LN(context) -> cn (B,N,Cc) bf16 [float4 loads, 128B
//                contiguous per lane-octet — DRAM-granule aligned]
//   [1024,1152): LN(query) -> qn (B,N,Cq) bf16        [float4 loads]
// ---------------------------------------------------------------------------
__global__ __launch_bounds__(256) void prep_k(
    const float* __restrict__ query, const float* __restrict__ context,
    const float* __restrict__ Wq, const float* __restrict__ Wk,
    const float* __restrict__ Wv, const float* __restrict__ Wo,
    const float* __restrict__ gq, const float* __restrict__ betq,
    const float* __restrict__ gc, const float* __restrict__ betc,
    __hip_bfloat16* __restrict__ Wqt, __hip_bfloat16* __restrict__ Wkt,
    __hip_bfloat16* __restrict__ Wvt, __hip_bfloat16* __restrict__ Wot,
    __hip_bfloat16* __restrict__ qn, __hip_bfloat16* __restrict__ cn) {
    __shared__ float T[32][33];         // weight transpose tile
    __shared__ float SsA[32][16];       // ctx stats partials
    __shared__ float S2A[32][16];
    __shared__ float SsB[16][64];       // query stats partials
    __shared__ float S2B[16][64];
    __shared__ float Mu[64], Rs[64];

    const int bid = blockIdx.x;
    const int tid = threadIdx.x;

    if (bid < 512) {
        // ---------------- weight transpose ----------------
        const int x = bid & 15, y = (bid >> 4) & 7, z = bid >> 7;
        const float* W; __hip_bfloat16* Wt; int K;
        switch (z) {
            case 0: W = Wq; Wt = Wqt; K = CQ; break;
            case 1: W = Wk; Wt = Wkt; K = CC; break;
            case 2: W = Wv; Wt = Wvt; K = CC; break;
            default: W = Wo; Wt = Wot; K = CQ; break;
        }
        const int k0 = x * 32;
        if (k0 >= K) return;
        const int c0 = y * 32;
        const int tx = tid & 31, ty = tid >> 5;
        #pragma unroll
        for (int i = 0; i < 4; ++i) {
            const int r = ty + 8 * i;
            T[r][tx] = W[(size_t)(k0 + r) * CQ + c0 + tx];
        }
        __syncthreads();
        #pragma unroll
        for (int i = 0; i < 4; ++i) {
            const int r = ty + 8 * i;
            Wt[(size_t)(c0 + r) * K + k0 + tx] = __float2bfloat16(T[tx][r]);
        }
    } else if (bid < 1024) {
        // ------- pool + LN(context): float4 loads, register-resident -------
        // block = (wqc2 0..1, hq 0..31, b 0..7); 16 positions x 512 channels
        const int u    = bid - 512;
        const int wqc2 = u & 1, hq = (u >> 1) & 31, b = u >> 6;
        const int pp   = tid & 7;         // position-pair 0..7 (pos 2pp, 2pp+1)
        const int cg   = tid >> 3;        // channel group 0..31 (16 ch each)
        const int ch0  = cg * 16;

        // float4 covers source cols 4pp..4pp+3 -> pooled positions 2pp, 2pp+1
        const float* Cb = context + ((size_t)b * CC + ch0) * 4096
                        + (size_t)(2 * hq) * 64 + (32 * wqc2 + 4 * pp);
        float pv0[16], pv1[16];
        float ss0 = 0.f, ss1 = 0.f, s20 = 0.f, s21 = 0.f;
        #pragma unroll
        for (int i = 0; i < 16; ++i) {
            const float4 r0 = *(const float4*)(Cb + (size_t)i * 4096);
            const float4 r1 = *(const float4*)(Cb + (size_t)i * 4096 + 64);
            const float v0 = (r0.x + r0.y + r1.x + r1.y) * 0.25f;
            const float v1 = (r0.z + r0.w + r1.z + r1.w) * 0.25f;
            pv0[i] = v0; pv1[i] = v1;
            ss0 += v0; s20 += v0 * v0;
            ss1 += v1; s21 += v1 * v1;
        }
        SsA[cg][2 * pp]     = ss0; S2A[cg][2 * pp]     = s20;
        SsA[cg][2 * pp + 1] = ss1; S2A[cg][2 * pp + 1] = s21;
        __syncthreads();
        if (tid < 16) {
            float ts = 0.f, t2 = 0.f;
            #pragma unroll
            for (int i = 0; i < 32; ++i) { ts += SsA[i][tid]; t2 += S2A[i][tid]; }
            const float mu  = ts * (1.f / CC);
            const float var = t2 * (1.f / CC) - mu * mu;
            Mu[tid] = mu; Rs[tid] = rsqrtf(var + 1e-5f);
        }
        __syncthreads();
        const float mu0 = Mu[2 * pp],     rs0 = Rs[2 * pp];
        const float mu1 = Mu[2 * pp + 1], rs1 = Rs[2 * pp + 1];
        const int pos0 = hq * 32 + wqc2 * 16 + 2 * pp;
        unsigned short* dst = (unsigned short*)cn
            + ((size_t)b * N_ + pos0) * CC + ch0;
        ushort8 a0, a1, b0, b1;
        #pragma unroll
        for (int i = 0; i < 8; ++i) {
            a0[i] = f2bf((pv0[i] - mu0) * rs0 * gc[ch0 + i] + betc[ch0 + i]);
            b0[i] = f2bf((pv1[i] - mu1) * rs1 * gc[ch0 + i] + betc[ch0 + i]);
        }
        #pragma unroll
        for (int i = 0; i < 8; ++i) {
            a1[i] = f2bf((pv0[8 + i] - mu0) * rs0 * gc[ch0 + 8 + i] + betc[ch0 + 8 + i]);
            b1[i] = f2bf((pv1[8 + i] - mu1) * rs1 * gc[ch0 + 8 + i] + betc[ch0 + 8 + i]);
        }
        *(ushort8*)(dst)          = a0;
        *(ushort8*)(dst + 8)      = a1;
        *(ushort8*)(dst + CC)     = b0;
        *(ushort8*)(dst + CC + 8) = b1;
    } else {
        // --------- LN(query): float4-along-n loads, register-resident ---------
        // block = (nt 0..15, b 0..7); 64 positions x 256 channels
        const int u  = bid - 1024;
        const int nt = u & 15, b = u >> 4;
        const int nq = tid & 15;          // n-quad: positions 4nq..4nq+3
        const int cg = tid >> 4;          // channel group 0..15 (16 ch each)
        const int ch0 = cg * 16;
        const int nb  = nt * 64 + 4 * nq;

        const float* Qb = query + ((size_t)b * CQ + ch0) * N_ + nb;
        float qv[64];
        float ps[4] = {0.f, 0.f, 0.f, 0.f};
        float p2[4] = {0.f, 0.f, 0.f, 0.f};
        #pragma unroll
        for (int i = 0; i < 16; ++i) {
            const float4 v = *(const float4*)(Qb + (size_t)i * N_);
            qv[4 * i + 0] = v.x; qv[4 * i + 1] = v.y;
            qv[4 * i + 2] = v.z; qv[4 * i + 3] = v.w;
            ps[0] += v.x; p2[0] += v.x * v.x;
            ps[1] += v.y; p2[1] += v.y * v.y;
            ps[2] += v.z; p2[2] += v.z * v.z;
            ps[3] += v.w; p2[3] += v.w * v.w;
        }
        #pragma unroll
        for (int j = 0; j < 4; ++j) {
            SsB[cg][4 * nq + j] = ps[j];
            S2B[cg][4 * nq + j] = p2[j];
        }
        __syncthreads();
        if (tid < 64) {
            float ts = 0.f, t2 = 0.f;
            #pragma unroll
            for (int i = 0; i < 16; ++i) { ts += SsB[i][tid]; t2 += S2B[i][tid]; }
            const float mu  = ts * (1.f / CQ);
            const float var = t2 * (1.f / CQ) - mu * mu;
            Mu[tid] = mu; Rs[tid] = rsqrtf(var + 1e-5f);
        }
        __syncthreads();
        #pragma unroll
        for (int j = 0; j < 4; ++j) {
            const float mu = Mu[4 * nq + j], rs = Rs[4 * nq + j];
            ushort8 o0, o1;
            #pragma unroll
            for (int i = 0; i < 8; ++i)
                o0[i] = f2bf((qv[4 * i + j] - mu) * rs * gq[ch0 + i] + betq[ch0 + i]);
            #pragma unroll
            for (int i = 0; i < 8; ++i)
                o1[i] = f2bf((qv[4 * (8 + i) + j] - mu) * rs * gq[ch0 + 8 + i] + betq[ch0 + 8 + i]);
            unsigned short* dst = (unsigned short*)qn
                + ((size_t)b * N_ + nb + j) * CQ + ch0;
            *(ushort8*)(dst)     = o0;
            *(ushort8*)(dst + 8) = o1;
        }
    }
}

// ---------------------------------------------------------------------------
// proj_all_k: Q projection (z>=8) and fused K+V projection (z<8) in one
// launch, reg-staged global prefetch. V columns written PERMUTED per
// 16-block (groups-of-4 1<->2 swap) so attention reads contiguous PV B-frags.
// grid (16, 4, 16), block 256.  [R9-exact]
// ---------------------------------------------------------------------------
__global__ __launch_bounds__(256) void proj_all_k(
    const __hip_bfloat16* __restrict__ qn, const __hip_bfloat16* __restrict__ cn,
    const __hip_bfloat16* __restrict__ Wqt, const __hip_bfloat16* __restrict__ Wkt,
    const __hip_bfloat16* __restrict__ Wvt,
    const float* __restrict__ bq, const float* __restrict__ bk,
    const float* __restrict__ bv,
    __hip_bfloat16* __restrict__ Qb, __hip_bfloat16* __restrict__ Kb,
    __hip_bfloat16* __restrict__ Vt, float qsc) {
    __shared__ unsigned short As[64][40];
    __shared__ unsigned short B1[64][40];
    __shared__ unsigned short B2[64][40];

    const int zz = blockIdx.z;
    const int n0 = blockIdx.x * 64;
    const int c0 = blockIdx.y * 64;
    const int tid = threadIdx.x;
    const int wid = tid >> 6, lane = tid & 63;
    const int lg = lane >> 4, ln = lane & 15;
    const int wn0 = (wid & 1) * 32, wc0 = (wid >> 1) * 32;
    const int sr = tid >> 2;
    const int sk = (tid & 3) * 8;

    if (zz >= 8) {
        // ---------------- Q projection (K = 256) ----------------
        const int b = zz - 8;
        const unsigned short* Ab = (const unsigned short*)qn + ((size_t)b * N_ + n0) * CQ;
        const unsigned short* Wb = (const unsigned short*)Wqt + (size_t)c0 * CQ;
        f32x4 acc[2][2] = {};
        ushort8 ra = *(const ushort8*)(Ab + (size_t)sr * CQ + sk);
        ushort8 rw = *(const ushort8*)(Wb + (size_t)sr * CQ + sk);
        for (int t = 0; t < 8; ++t) {
            *(ushort8*)&As[sr][sk] = ra;
            *(ushort8*)&B1[sr][sk] = rw;
            __syncthreads();
            if (t < 7) {
                ra = *(const ushort8*)(Ab + (size_t)sr * CQ + (t + 1) * 32 + sk);
                rw = *(const ushort8*)(Wb + (size_t)sr * CQ + (t + 1) * 32 + sk);
            }
            bf16x8 a[2], w[2];
            #pragma unroll
            for (int i = 0; i < 2; ++i) a[i] = ldb8(&As[wn0 + 16 * i + ln][8 * lg]);
            #pragma unroll
            for (int j = 0; j < 2; ++j) w[j] = ldb8(&B1[wc0 + 16 * j + ln][8 * lg]);
            #pragma unroll
            for (int i = 0; i < 2; ++i)
                #pragma unroll
                for (int j = 0; j < 2; ++j)
                    acc[i][j] = __builtin_amdgcn_mfma_f32_16x16x32_bf16(a[i], w[j], acc[i][j], 0, 0, 0);
            __syncthreads();
        }
        #pragma unroll
        for (int j = 0; j < 2; ++j) {
            const int co = c0 + wc0 + 16 * j + ln;
            const int h = co >> 5, d = co & 31;
            const float bb = bq[co];
            #pragma unroll
            for (int i = 0; i < 2; ++i)
                #pragma unroll
                for (int r = 0; r < 4; ++r) {
                    const int n = n0 + wn0 + 16 * i + 4 * lg + r;
                    Qb[(((size_t)b * NH + h) * N_ + n) * HD + d] =
                        __float2bfloat16((acc[i][j][r] + bb) * qsc);
                }
        }
    } else {
        // ---------------- K + V projection (K = 512) ----------------
        const int b = zz;
        const unsigned short* Ab  = (const unsigned short*)cn + ((size_t)b * N_ + n0) * CC;
        const unsigned short* Wkb = (const unsigned short*)Wkt + (size_t)c0 * CC;
        const unsigned short* Wvb = (const unsigned short*)Wvt + (size_t)c0 * CC;
        f32x4 accK[2][2] = {};
        f32x4 accV[2][2] = {};
        ushort8 ra = *(const ushort8*)(Ab  + (size_t)sr * CC + sk);
        ushort8 rk = *(const ushort8*)(Wkb + (size_t)sr * CC + sk);
        ushort8 rv = *(const ushort8*)(Wvb + (size_t)sr * CC + sk);
        for (int t = 0; t < 16; ++t) {
            *(ushort8*)&As[sr][sk] = ra;
            *(ushort8*)&B1[sr][sk] = rk;
            *(ushort8*)&B2[sr][sk] = rv;
            __syncthreads();
            if (t < 15) {
                ra = *(const ushort8*)(Ab  + (size_t)sr * CC + (t + 1) * 32 + sk);
                rk = *(const ushort8*)(Wkb + (size_t)sr * CC + (t + 1) * 32 + sk);
                rv = *(const ushort8*)(Wvb + (size_t)sr * CC + (t + 1) * 32 + sk);
            }
            bf16x8 a[2], wk[2], wv[2];
            #pragma unroll
            for (int i = 0; i < 2; ++i) {
                a[i]  = ldb8(&As[wn0 + 16 * i + ln][8 * lg]);
                wk[i] = ldb8(&B1[wc0 + 16 * i + ln][8 * lg]);
                wv[i] = ldb8(&B2[wc0 + 16 * i + ln][8 * lg]);
            }
            #pragma unroll
            for (int i = 0; i < 2; ++i)
                #pragma unroll
                for (int j = 0; j < 2; ++j) {
                    accK[i][j] = __builtin_amdgcn_mfma_f32_16x16x32_bf16(a[i], wk[j], accK[i][j], 0, 0, 0);
                    accV[i][j] = __builtin_amdgcn_mfma_f32_16x16x32_bf16(a[i], wv[j], accV[i][j], 0, 0, 0);
                }
            __syncthreads();
        }
        #pragma unroll
        for (int j = 0; j < 2; ++j) {
            const int co = c0 + wc0 + 16 * j + ln;
            const int h = co >> 5, d = co & 31;
            const float bbk = bk[co], bbv = bv[co];
            #pragma unroll
            for (int i = 0; i < 2; ++i) {
                const int nb = n0 + wn0 + 16 * i + 4 * lg;
                #pragma unroll
                for (int r = 0; r < 4; ++r)
                    Kb[(((size_t)b * NH + h) * N_ + nb + r) * HD + d] =
                        __float2bfloat16(accK[i][j][r] + bbk);
                ushort4v o;
                #pragma unroll
                for (int r = 0; r < 4; ++r) o[r] = f2bf(accV[i][j][r] + bbv);
                // permuted column write: 4-groups 1<->2 swap within 16-block
                const int g  = (nb >> 2) & 3;
                const int gp = ((g & 1) << 1) | (g >> 1);
                const int nbp = (nb & ~15) | (gp << 2);
                *(ushort4v*)((unsigned short*)Vt + (((size_t)b * NH + h) * HD + d) * N_ + nbp) = o;
            }
        }
    }
}

// ---------------------------------------------------------------------------
// 32x32 swapped-QK^T flash attention, in-register max-free softmax,
// 4-way kv-split: block = one 32-row q-subtile, 4 waves = 4 kv-quarters.
// 2-deep K prefetch + top-of-step V loads. grid (32, 64) XCD-swizzled.
// [single experimental change vs R9]
// ---------------------------------------------------------------------------
__global__ __launch_bounds__(256) void attn32_k(
    const __hip_bfloat16* __restrict__ Q,
    const __hip_bfloat16* __restrict__ K,
    const __hip_bfloat16* __restrict__ Vt,
    __hip_bfloat16* __restrict__ O) {
    __shared__ float accS[3][64][20];
    __shared__ float lwS[3][64];

    const int lin = blockIdx.x + 32 * blockIdx.y;
    const int eff = (lin & 7) * 256 + (lin >> 3);   // 2048 blocks, 8 XCDs
    const int qt  = eff & 31;
    const int bh  = eff >> 5;
    const int b   = bh >> 3;
    const int h   = bh & 7;
    const int wid  = threadIdx.x >> 6;   // kv quarter 0..3
    const int lane = threadIdx.x & 63;
    const int l31  = lane & 31;
    const int hh   = lane >> 5;
    const int q0   = qt * 32;

    const unsigned short* Qp = (const unsigned short*)Q + ((size_t)bh * N_ + q0) * HD;
    const unsigned short* Kbb = (const unsigned short*)K + (size_t)bh * N_ * HD;
    const unsigned short* Vb = (const unsigned short*)Vt + ((size_t)bh * HD + l31) * N_;

    bf16x8 qB[2];
    #pragma unroll
    for (int m = 0; m < 2; ++m)
        qB[m] = ldb8(Qp + (size_t)l31 * HD + 16 * m + 8 * hh);

    const f32x16 Z = {0.f,0.f,0.f,0.f,0.f,0.f,0.f,0.f,
                      0.f,0.f,0.f,0.f,0.f,0.f,0.f,0.f};
    f32x16 acc = Z;
    float ls0 = 0.f, ls1 = 0.f, ls2 = 0.f, ls3 = 0.f;

    const int kvbase = wid * 256;
    const unsigned short* kp = Kbb + (size_t)(kvbase + l31) * HD + 8 * hh;
    const unsigned short* vp = Vb + kvbase + 8 * hh;

    bf16x8 kaA[2][4];
    #pragma unroll
    for (int j = 0; j < 4; ++j)
        kaA[0][j] = ldb8(kp + (j >> 1) * 1024 + (j & 1) * 16);

    #pragma unroll
    for (int st = 0; st < 4; ++st) {
        const int cur = st & 1;
        bf16x8 va[4];
        #pragma unroll
        for (int j = 0; j < 4; ++j)
            va[j] = ldb8(vp + st * 64 + 16 * j);
        if (st < 3) {
            const unsigned short* kp2 = kp + (size_t)(st + 1) * 2048;
            #pragma unroll
            for (int j = 0; j < 4; ++j)
                kaA[cur ^ 1][j] = ldb8(kp2 + (j >> 1) * 1024 + (j & 1) * 16);
        }

        f32x16 s0, s1;
        s0 = __builtin_amdgcn_mfma_f32_32x32x16_bf16(kaA[cur][0], qB[0], Z, 0, 0, 0);
        s0 = __builtin_amdgcn_mfma_f32_32x32x16_bf16(kaA[cur][1], qB[1], s0, 0, 0, 0);
        s1 = __builtin_amdgcn_mfma_f32_32x32x16_bf16(kaA[cur][2], qB[0], Z, 0, 0, 0);
        s1 = __builtin_amdgcn_mfma_f32_32x32x16_bf16(kaA[cur][3], qB[1], s1, 0, 0, 0);

        unsigned int pk[2][4][2];
        #pragma unroll
        for (int T = 0; T < 2; ++T) {
            float p[16];
            #pragma unroll
            for (int r = 0; r < 16; ++r)
                p[r] = __builtin_amdgcn_exp2f(T == 0 ? s0[r] : s1[r]);
            #pragma unroll
            for (int r = 0; r < 16; r += 4) {
                ls0 += p[r]; ls1 += p[r + 1]; ls2 += p[r + 2]; ls3 += p[r + 3];
            }
            #pragma unroll
            for (int c = 0; c < 4; ++c) {
                asm("v_cvt_pk_bf16_f32 %0, %1, %2"
                    : "=v"(pk[T][c][0]) : "v"(p[4 * c]), "v"(p[4 * c + 1]));
                asm("v_cvt_pk_bf16_f32 %0, %1, %2"
                    : "=v"(pk[T][c][1]) : "v"(p[4 * c + 2]), "v"(p[4 * c + 3]));
            }
        }

        #pragma unroll
        for (int w = 0; w < 4; ++w) {
            const int T = w >> 1, cp = w & 1;
            uint4v fu = {pk[T][2 * cp][0], pk[T][2 * cp][1],
                         pk[T][2 * cp + 1][0], pk[T][2 * cp + 1][1]};
            const bf16x8 pa = __builtin_bit_cast(bf16x8, fu);
            acc = __builtin_amdgcn_mfma_f32_32x32x16_bf16(pa, va[w], acc, 0, 0, 0);
        }
    }

    const float lsum = (ls0 + ls1) + (ls2 + ls3);
    const float lw = lsum + __shfl_xor(lsum, 32);

    if (wid > 0) {
        #pragma unroll
        for (int r4 = 0; r4 < 4; ++r4) {
            float4 v = {acc[4 * r4], acc[4 * r4 + 1], acc[4 * r4 + 2], acc[4 * r4 + 3]};
            *(float4*)&accS[wid - 1][lane][4 * r4] = v;
        }
        lwS[wid - 1][lane] = lw;
    }
    __syncthreads();
    if (wid == 0) {
        const float ltot = lw + lwS[0][lane] + lwS[1][lane] + lwS[2][lane];
        const float linv = 1.0f / ltot;
        #pragma unroll
        for (int r = 0; r < 16; ++r) {
            const int ql = (r & 3) + 8 * (r >> 2) + 4 * hh;
            const float vv = (acc[r] + accS[0][lane][r] + accS[1][lane][r]
                              + accS[2][lane][r]) * __shfl(linv, ql);
            O[((size_t)b * N_ + q0 + ql) * CQ + h * HD + l31] = __float2bfloat16(vv);
        }
    }
}

// ---------------------------------------------------------------------------
// Output projection + bias + residual with reg-staged prefetch.
// grid (16, 4, B), block 256.  [R9-exact]
// ---------------------------------------------------------------------------
__global__ __launch_bounds__(256) void out_proj_k(const __hip_bfloat16* __restrict__ Ob,
                              const __hip_bfloat16* __restrict__ Wot,
                              const float* __restrict__ bo,
                              const float* __restrict__ query,
                              float* __restrict__ out) {
    __shared__ unsigned short As[64][40];
    __shared__ unsigned short Bs[64][40];
    const int b  = blockIdx.z;
    const int n0 = blockIdx.x * 64;
    const int c0 = blockIdx.y * 64;
    const int tid = threadIdx.x;
    const int wid = tid >> 6, lane = tid & 63;
    const int lg = lane >> 4, ln = lane & 15;
    const int wn0 = (wid & 1) * 32, wc0 = (wid >> 1) * 32;

    const unsigned short* Ab = (const unsigned short*)Ob + ((size_t)b * N_ + n0) * CQ;
    const unsigned short* Wb = (const unsigned short*)Wot + (size_t)c0 * CQ;
    const int sr = tid >> 2;
    const int sk = (tid & 3) * 8;

    f32x4 acc[2][2] = {};
    ushort8 ra = *(const ushort8*)(Ab + (size_t)sr * CQ + sk);
    ushort8 rw = *(const ushort8*)(Wb + (size_t)sr * CQ + sk);

    for (int t = 0; t < 8; ++t) {
        *(ushort8*)&As[sr][sk] = ra;
        *(ushort8*)&Bs[sr][sk] = rw;
        __syncthreads();
        if (t < 7) {
            ra = *(const ushort8*)(Ab + (size_t)sr * CQ + (t + 1) * 32 + sk);
            rw = *(const ushort8*)(Wb + (size_t)sr * CQ + (t + 1) * 32 + sk);
        }
        bf16x8 a[2], w[2];
        #pragma unroll
        for (int i = 0; i < 2; ++i)
            a[i] = ldb8(&As[wn0 + 16 * i + ln][8 * lg]);
        #pragma unroll
        for (int j = 0; j < 2; ++j)
            w[j] = ldb8(&Bs[wc0 + 16 * j + ln][8 * lg]);
        #pragma unroll
        for (int i = 0; i < 2; ++i)
            #pragma unroll
            for (int j = 0; j < 2; ++j)
                acc[i][j] = __builtin_amdgcn_mfma_f32_16x16x32_bf16(a[i], w[j], acc[i][j], 0, 0, 0);
        __syncthreads();
    }

    #pragma unroll
    for (int j = 0; j < 2; ++j) {
        const int co = c0 + wc0 + 16 * j + ln;
        const float bb = bo[co];
        #pragma unroll
        for (int i = 0; i < 2; ++i) {
            const int nb = n0 + wn0 + 16 * i + 4 * lg;
            const float4 res = *(const float4*)&query[((size_t)b * CQ + co) * N_ + nb];
            float4 o;
            o.x = acc[i][j][0] + bb + res.x;
            o.y = acc[i][j][1] + bb + res.y;
            o.z = acc[i][j][2] + bb + res.z;
            o.w = acc[i][j][3] + bb + res.w;
            *(float4*)&out[((size_t)b * CQ + co) * N_ + nb] = o;
        }
    }
}

// ---------------------------------------------------------------------------
extern "C" void kernel_launch(void* const* d_in, const int* in_sizes, int n_in,
                              void* d_out, int out_size, void* d_ws, size_t ws_size,
                              hipStream_t stream) {
    const float* query   = (const float*)d_in[0];
    const float* context = (const float*)d_in[1];
    const float* Wq = (const float*)d_in[2];
    const float* bq = (const float*)d_in[3];
    const float* Wk = (const float*)d_in[4];
    const float* bk = (const float*)d_in[5];
    const float* Wv = (const float*)d_in[6];
    const float* bv = (const float*)d_in[7];
    const float* Wo = (const float*)d_in[8];
    const float* bo = (const float*)d_in[9];
    const float* gq   = (const float*)d_in[10];
    const float* betq = (const float*)d_in[11];
    const float* gc   = (const float*)d_in[12];
    const float* betc = (const float*)d_in[13];
    float* out = (float*)d_out;

    char* w = (char*)d_ws;
    __hip_bfloat16* qn  = (__hip_bfloat16*)w;  w += (size_t)B_ * N_ * CQ * 2;
    __hip_bfloat16* cn  = (__hip_bfloat16*)w;  w += (size_t)B_ * N_ * CC * 2;
    __hip_bfloat16* Qb  = (__hip_bfloat16*)w;  w += (size_t)B_ * NH * N_ * HD * 2;
    __hip_bfloat16* Kb  = (__hip_bfloat16*)w;  w += (size_t)B_ * NH * N_ * HD * 2;
    __hip_bfloat16* Vt  = (__hip_bfloat16*)w;  w += (size_t)B_ * NH * HD * N_ * 2;
    __hip_bfloat16* Ob  = (__hip_bfloat16*)w;  w += (size_t)B_ * N_ * CQ * 2;
    __hip_bfloat16* Wqt = (__hip_bfloat16*)w;  w += (size_t)CQ * CQ * 2;
    __hip_bfloat16* Wkt = (__hip_bfloat16*)w;  w += (size_t)CQ * CC * 2;
    __hip_bfloat16* Wvt = (__hip_bfloat16*)w;  w += (size_t)CQ * CC * 2;
    __hip_bfloat16* Wot = (__hip_bfloat16*)w;  w += (size_t)CQ * CQ * 2;

    prep_k<<<dim3(1152), 256, 0, stream>>>(query, context, Wq, Wk, Wv, Wo,
                                           gq, betq, gc, betc,
                                           Wqt, Wkt, Wvt, Wot, qn, cn);

    // scale includes log2(e) so the softmax exp becomes a bare v_exp_f32
    const float qsc = 0.17677669529663687f * 1.4426950408889634f;
    proj_all_k<<<dim3(16, 4, 16), 256, 0, stream>>>(qn, cn, Wqt, Wkt, Wvt,
                                                    bq, bk, bv, Qb, Kb, Vt, qsc);

    attn32_k<<<dim3(32, 64), 256, 0, stream>>>(Qb, Kb, Vt, Ob);

    out_proj_k<<<dim3(16, 4, 8), 256, 0, stream>>>(Ob, Wot, bo, query, out);
}